// Round 1
// baseline (37.767 us; speedup 1.0000x reference)
//
#include <hip/hip_runtime.h>
#include <math.h>

// Problem constants (match reference setup_inputs)
#define BATCH   8192
#define NCOLS   67      // col0 = user idx, cols 1..66 = item indices
#define DFAC    64      // embedding dim
#define NNEG    64      // negatives = cols 3..66
#define THREADS 256
#define WAVES_PER_BLOCK (THREADS / 64)
#define ROWS_PER_WAVE 2
#define NBLOCKS (BATCH / (ROWS_PER_WAVE * WAVES_PER_BLOCK))   // 1024

// stable softplus: log(1+exp(t))
__device__ __forceinline__ float softplus_f(float t) {
    return fmaxf(t, 0.f) + log1pf(expf(-fabsf(t)));
}
// jax.nn.log_sigmoid(x) = -softplus(-x)
__device__ __forceinline__ float logsig_f(float x) { return -softplus_f(-x); }

__device__ __forceinline__ float wave_sum(float v) {
    #pragma unroll
    for (int off = 32; off; off >>= 1) v += __shfl_xor(v, off);
    return v;
}
__device__ __forceinline__ float wave_max(float v) {
    #pragma unroll
    for (int off = 32; off; off >>= 1) v = fmaxf(v, __shfl_xor(v, off));
    return v;
}

__global__ __launch_bounds__(THREADS) void bpr_main(
    const int*   __restrict__ one_batch,
    const float* __restrict__ eu,
    const float* __restrict__ ei,
    float*       __restrict__ partials)   // [NBLOCKS*3]
{
    const int lane = threadIdx.x & 63;
    const int wave = threadIdx.x >> 6;
    const int gwave = blockIdx.x * WAVES_PER_BLOCK + wave;

    float acc_pos = 0.f;   // sum of log_sigmoid(2*pos_sim1 - m6max)   (lane 0)
    float acc_m6  = 0.f;   // per-lane partial of sum(one_pn)
    float acc_l2  = 0.f;   // per-lane partial of l2 row sums

    #pragma unroll
    for (int rr = 0; rr < ROWS_PER_WAVE; ++rr) {
        const int r = gwave * ROWS_PER_WAVE + rr;
        const int* idx = one_batch + r * NCOLS;

        int uidx = __builtin_amdgcn_readfirstlane(idx[0]);
        const float4* urow = (const float4*)(eu + (size_t)uidx * DFAC);

        // lane n owns negative n -> item column 3+n
        const int nidx = idx[3 + lane];
        const float4* vrow = (const float4*)(ei + (size_t)nidx * DFAC);

        float zak = 0.f, vsq = 0.f, usq = 0.f;
        #pragma unroll
        for (int q = 0; q < DFAC / 4; ++q) {
            const float4 uq = urow[q];   // wave-uniform -> scalar loads
            const float4 vq = vrow[q];   // scattered per-lane float4
            zak += uq.x * vq.x + uq.y * vq.y + uq.z * vq.z + uq.w * vq.w;
            vsq += vq.x * vq.x + vq.y * vq.y + vq.z * vq.z + vq.w * vq.w;
            usq += uq.x * uq.x + uq.y * uq.y + uq.z * uq.z + uq.w * uq.w;
        }

        // lanes 0,1 compute the positive-pair dots (cols 1,2)
        float dot2 = 0.f, vsq2 = 0.f;
        if (lane < 2) {
            const int it2 = idx[1 + lane];
            const float4* w2 = (const float4*)(ei + (size_t)it2 * DFAC);
            #pragma unroll
            for (int q = 0; q < DFAC / 4; ++q) {
                const float4 uq = urow[q];
                const float4 vq = w2[q];
                dot2 += uq.x * vq.x + uq.y * vq.y + uq.z * vq.z + uq.w * vq.w;
                vsq2 += vq.x * vq.x + vq.y * vq.y + vq.z * vq.z + vq.w * vq.w;
            }
        }
        const float z_ai = __shfl(dot2, 0);
        const float z_aj = __shfl(dot2, 1);

        // one_pn[n] = -logsig(z_ai - zak) - logsig(z_aj - zak)
        const float one_pn = softplus_f(zak - z_ai) + softplus_f(zak - z_aj);
        acc_m6 += one_pn;
        acc_l2 += vsq + vsq2;
        if (lane == 0) acc_l2 += usq;   // usq is wave-uniform; count once

        const float m6max = wave_max(one_pn);
        if (lane == 0) {
            const float dd  = fabsf(z_ai - z_aj);
            const float pos = fminf(dd, 0.5f);
            acc_pos += logsig_f(pos * 2.f - m6max);
        }
    }

    acc_m6 = wave_sum(acc_m6);
    acc_l2 = wave_sum(acc_l2);

    __shared__ float red[WAVES_PER_BLOCK][3];
    if (lane == 0) {
        red[wave][0] = acc_pos;
        red[wave][1] = acc_m6;
        red[wave][2] = acc_l2;
    }
    __syncthreads();
    if (threadIdx.x == 0) {
        float p = 0.f, m = 0.f, l = 0.f;
        #pragma unroll
        for (int w = 0; w < WAVES_PER_BLOCK; ++w) {
            p += red[w][0]; m += red[w][1]; l += red[w][2];
        }
        partials[blockIdx.x * 3 + 0] = p;
        partials[blockIdx.x * 3 + 1] = m;
        partials[blockIdx.x * 3 + 2] = l;
    }
}

__global__ __launch_bounds__(256) void bpr_finalize(
    const float* __restrict__ partials, float* __restrict__ out)
{
    float p = 0.f, m = 0.f, l = 0.f;
    for (int i = threadIdx.x; i < NBLOCKS; i += 256) {
        p += partials[i * 3 + 0];
        m += partials[i * 3 + 1];
        l += partials[i * 3 + 2];
    }
    p = wave_sum(p); m = wave_sum(m); l = wave_sum(l);

    __shared__ float red[4][3];
    const int lane = threadIdx.x & 63, wave = threadIdx.x >> 6;
    if (lane == 0) { red[wave][0] = p; red[wave][1] = m; red[wave][2] = l; }
    __syncthreads();
    if (threadIdx.x == 0) {
        #pragma unroll
        for (int w = 1; w < 4; ++w) { p += red[w][0]; m += red[w][1]; l += red[w][2]; }
        const float inv = 1.f / (float)BATCH;
        const float l2   = 0.01f * l * inv;
        const float loss = (-p * inv) + m * inv + l2;
        out[0] = loss;
        out[1] = l2;
    }
}

extern "C" void kernel_launch(void* const* d_in, const int* in_sizes, int n_in,
                              void* d_out, int out_size, void* d_ws, size_t ws_size,
                              hipStream_t stream) {
    const int*   one_batch = (const int*)d_in[0];
    const float* eu        = (const float*)d_in[1];
    const float* ei        = (const float*)d_in[2];
    float* out = (float*)d_out;
    float* partials = (float*)d_ws;   // NBLOCKS*3 floats = 12 KB

    bpr_main<<<NBLOCKS, THREADS, 0, stream>>>(one_batch, eu, ei, partials);
    bpr_finalize<<<1, 256, 0, stream>>>(partials, out);
}

// Round 2
// 23.551 us; speedup vs baseline: 1.6036x; 1.6036x over previous
//
#include <hip/hip_runtime.h>
#include <math.h>

// Problem constants (match reference setup_inputs)
#define BATCH   8192
#define NCOLS   67      // col0 = user idx, cols 1..66 = item indices
#define DFAC    64      // embedding dim
#define THREADS 256
#define WPB     4       // waves per block; 1 batch row per wave
#define NBLOCKS (BATCH / WPB)   // 2048

// stable softplus: log(1+exp(t))
__device__ __forceinline__ float softplus_f(float t) {
    return fmaxf(t, 0.f) + log1pf(expf(-fabsf(t)));
}
// jax.nn.log_sigmoid(x) = -softplus(-x)
__device__ __forceinline__ float logsig_f(float x) { return -softplus_f(-x); }

__device__ __forceinline__ float wave_sum(float v) {
    #pragma unroll
    for (int off = 32; off; off >>= 1) v += __shfl_xor(v, off);
    return v;
}
__device__ __forceinline__ float wave_max(float v) {
    #pragma unroll
    for (int off = 32; off; off >>= 1) v = fmaxf(v, __shfl_xor(v, off));
    return v;
}

// One wave handles one batch row.
// Gather is coalesced: 4 lanes (rl=lane&3) cooperate on one item row; each
// load instruction covers 16 item rows as 16 dense 64B segments (vs 64
// scattered 16B requests in the naive one-lane-per-row mapping).
__global__ __launch_bounds__(THREADS) void bpr_main(
    const int*   __restrict__ one_batch,
    const float* __restrict__ eu,
    const float* __restrict__ ei,
    float*       __restrict__ partials)   // [NBLOCKS*3]
{
    const int lane = threadIdx.x & 63;
    const int wave = threadIdx.x >> 6;
    const int r    = blockIdx.x * WPB + wave;

    const int rl = lane & 3;    // lane-within-row (16B chunk owner)
    const int rg = lane >> 2;   // row-group 0..15 (which item row this iter)

    __shared__ float zbuf[WPB][68];   // z[col] for col = 1..66

    const int* idx = one_batch + r * NCOLS;

    // Per-lane copies of the 67 indices (coalesced, 2 loads).
    const int myidx  = idx[lane];                        // cols 0..63
    const int myidx2 = idx[64 + (lane < 3 ? lane : 2)];  // cols 64..66 on lanes 0..2

    const int uidx = __builtin_amdgcn_readfirstlane(myidx);  // col 0 = user

    // u chunks: u4[j] holds dims [j*16 + rl*4, +4). The 4 lanes of a row
    // group jointly hold all 64 dims; 16 groups replicate.
    float4 u4[4];
    #pragma unroll
    for (int j = 0; j < 4; ++j)
        u4[j] = *(const float4*)(eu + (size_t)uidx * DFAC + j * 16 + rl * 4);

    float usq = 0.f;
    #pragma unroll
    for (int j = 0; j < 4; ++j)
        usq += u4[j].x*u4[j].x + u4[j].y*u4[j].y + u4[j].z*u4[j].z + u4[j].w*u4[j].w;

    float acc_sq = 0.f;   // per-lane partial of item squared-norms (valid rows only)

    #pragma unroll
    for (int s = 0; s < 5; ++s) {
        const int  rr    = s * 16 + rg;      // 0..79; item col = 1+rr
        const bool valid = (rr < 66);
        int col = 1 + rr;
        if (col > 66) col = 66;              // clamp for safe (discarded) load
        const int ridx = (col < 64) ? __shfl(myidx, col)
                                    : __shfl(myidx2, col - 64);

        const float* vrow = ei + (size_t)ridx * DFAC + rl * 4;
        float pd = 0.f, sq = 0.f;
        #pragma unroll
        for (int j = 0; j < 4; ++j) {
            const float4 v4 = *(const float4*)(vrow + j * 16);
            pd += v4.x*u4[j].x + v4.y*u4[j].y + v4.z*u4[j].z + v4.w*u4[j].w;
            sq += v4.x*v4.x + v4.y*v4.y + v4.z*v4.z + v4.w*v4.w;
        }
        if (valid) acc_sq += sq;             // per-lane partial (unreduced)

        // reduce dot across the 4-lane row group
        pd += __shfl_xor(pd, 1);
        pd += __shfl_xor(pd, 2);
        if (valid && rl == 0) zbuf[wave][col] = pd;
    }

    // Same-wave LDS write->read; compiler inserts the lgkmcnt wait.
    const float z_ai = zbuf[wave][1];
    const float z_aj = zbuf[wave][2];
    const float zak  = zbuf[wave][3 + lane];   // negative owned by this lane

    // one_pn[n] = -logsig(z_ai - zak) - logsig(z_aj - zak)
    const float one_pn = softplus_f(zak - z_ai) + softplus_f(zak - z_aj);

    const float m6max = wave_max(one_pn);

    float acc_pos = 0.f;
    if (lane == 0) {
        const float dd  = fabsf(z_ai - z_aj);
        const float pos = fminf(dd, 0.5f);
        acc_pos = logsig_f(pos * 2.f - m6max);
    }

    // l2 row total = sum item vsq (acc_sq) + usq (replicated 16x -> /16)
    const float acc_m6 = wave_sum(one_pn);
    const float acc_l2 = wave_sum(acc_sq + usq * 0.0625f);

    __shared__ float red[WPB][3];
    if (lane == 0) {
        red[wave][0] = acc_pos;
        red[wave][1] = acc_m6;
        red[wave][2] = acc_l2;
    }
    __syncthreads();
    if (threadIdx.x == 0) {
        float p = 0.f, m = 0.f, l = 0.f;
        #pragma unroll
        for (int w = 0; w < WPB; ++w) {
            p += red[w][0]; m += red[w][1]; l += red[w][2];
        }
        partials[blockIdx.x * 3 + 0] = p;
        partials[blockIdx.x * 3 + 1] = m;
        partials[blockIdx.x * 3 + 2] = l;
    }
}

__global__ __launch_bounds__(256) void bpr_finalize(
    const float* __restrict__ partials, float* __restrict__ out)
{
    float p = 0.f, m = 0.f, l = 0.f;
    for (int i = threadIdx.x; i < NBLOCKS; i += 256) {
        p += partials[i * 3 + 0];
        m += partials[i * 3 + 1];
        l += partials[i * 3 + 2];
    }
    p = wave_sum(p); m = wave_sum(m); l = wave_sum(l);

    __shared__ float red[4][3];
    const int lane = threadIdx.x & 63, wave = threadIdx.x >> 6;
    if (lane == 0) { red[wave][0] = p; red[wave][1] = m; red[wave][2] = l; }
    __syncthreads();
    if (threadIdx.x == 0) {
        #pragma unroll
        for (int w = 1; w < 4; ++w) { p += red[w][0]; m += red[w][1]; l += red[w][2]; }
        const float inv = 1.f / (float)BATCH;
        const float l2   = 0.01f * l * inv;
        const float loss = (-p * inv) + m * inv + l2;
        out[0] = loss;
        out[1] = l2;
    }
}

extern "C" void kernel_launch(void* const* d_in, const int* in_sizes, int n_in,
                              void* d_out, int out_size, void* d_ws, size_t ws_size,
                              hipStream_t stream) {
    const int*   one_batch = (const int*)d_in[0];
    const float* eu        = (const float*)d_in[1];
    const float* ei        = (const float*)d_in[2];
    float* out = (float*)d_out;
    float* partials = (float*)d_ws;   // NBLOCKS*3 floats = 24 KB

    bpr_main<<<NBLOCKS, THREADS, 0, stream>>>(one_batch, eu, ei, partials);
    bpr_finalize<<<1, 256, 0, stream>>>(partials, out);
}